// Round 4
// baseline (163.850 us; speedup 1.0000x reference)
//
#include <hip/hip_runtime.h>
#include <stdint.h>

#define IN_F   4096
#define OUT_F  11008
#define BATCH  8
#define NS     32                 // split-K slices
#define SLICE  (IN_F / NS)        // 128 i per slice
#define ICH    16                 // i consumed per lane-iter (= one 64B line of each array)
#define RGRPS  (OUT_F / 256)      // 43 row groups of 256 rows

// out[b][o] = bias[o]  (out is not re-poisoned between replays; re-init every call)
__global__ void qins_init(const float* __restrict__ bias, float* __restrict__ out)
{
    const int o = blockIdx.x * 256 + threadIdx.x;
    const float bv = bias[o];
#pragma unroll
    for (int b = 0; b < BATCH; ++b)
        out[(size_t)b * OUT_F + o] = bv;
}

__global__ __launch_bounds__(256, 4)
void qins_main(const float* __restrict__ x,
               const int*   __restrict__ stored,
               const int*   __restrict__ sign,
               const float* __restrict__ log_min,
               const float* __restrict__ log_max,
               float* __restrict__ out)
{
    // s-major decomposition: consecutive blocks share the x slice, scatter atomics
    const int rg  = blockIdx.x % RGRPS;
    const int s   = blockIdx.x / RGRPS;
    const int row = rg * 256 + threadIdx.x;      // one output row per thread
    const int i0  = s * SLICE;

    const float lmin = log_min[0];
    const float lmax = log_max[0];
    const float L2E  = 1.44269504088896340736f;
    // log2(|w|) = d0 + code*d1
    const float d1 = -(lmax - lmin) * (L2E / 254.0f);
    const float d0 = (lmin + (lmax - lmin) * (255.0f / 254.0f)) * L2E;

    float acc[BATCH];
#pragma unroll
    for (int b = 0; b < BATCH; ++b) acc[b] = 0.0f;

    const int base = row * IN_F + i0;            // < 2^26, 32-bit safe

    for (int it = 0; it < SLICE; it += ICH) {
        // one full 64B line of codes + one of signs per lane (no partial-line reuse)
        int4 c[4], g[4];
#pragma unroll
        for (int q = 0; q < 4; ++q) {
            c[q] = *reinterpret_cast<const int4*>(stored + base + it + 4 * q);
            g[q] = *reinterpret_cast<const int4*>(sign   + base + it + 4 * q);
        }

#pragma unroll
        for (int q = 0; q < 4; ++q) {
            float w[4];
            {
                const int cc[4] = { c[q].x, c[q].y, c[q].z, c[q].w };
                const int gg[4] = { g[q].x, g[q].y, g[q].z, g[q].w };
#pragma unroll
                for (int j = 0; j < 4; ++j) {
                    const float e = __builtin_amdgcn_exp2f(fmaf((float)cc[j], d1, d0));
                    const uint32_t m = ((uint32_t)gg[j]) & 0x80000000u;
                    w[j] = __uint_as_float(__float_as_uint(e) ^ m);
                }
            }
#pragma unroll
            for (int b = 0; b < BATCH; ++b) {
                // wave-uniform x addresses -> scalar loads, off the VMEM pipe
                const float* xb = x + b * IN_F + i0 + it + 4 * q;
                float a = acc[b];
                a = fmaf(w[0], xb[0], a);
                a = fmaf(w[1], xb[1], a);
                a = fmaf(w[2], xb[2], a);
                a = fmaf(w[3], xb[3], a);
                acc[b] = a;
            }
        }
    }

#pragma unroll
    for (int b = 0; b < BATCH; ++b)
        atomicAdd(out + (size_t)b * OUT_F + row, acc[b]);
}

extern "C" void kernel_launch(void* const* d_in, const int* in_sizes, int n_in,
                              void* d_out, int out_size, void* d_ws, size_t ws_size,
                              hipStream_t stream)
{
    const float* x      = (const float*)d_in[0];
    const int*   stored = (const int*)d_in[1];
    const int*   sign   = (const int*)d_in[2];
    const float* lmin   = (const float*)d_in[3];
    const float* lmax   = (const float*)d_in[4];
    const float* bias   = (const float*)d_in[5];
    float* out = (float*)d_out;

    qins_init<<<dim3(RGRPS), dim3(256), 0, stream>>>(bias, out);
    qins_main<<<dim3(RGRPS * NS), dim3(256), 0, stream>>>(x, stored, sign, lmin, lmax, out);
}

// Round 5
// 87.914 us; speedup vs baseline: 1.8638x; 1.8638x over previous
//
#include <hip/hip_runtime.h>
#include <stdint.h>

#define IN_F   4096
#define OUT_F  11008
#define BATCH  8
#define RPW    2          // output rows per wave
#define WAVES  4          // waves per block
#define RPB    (RPW*WAVES)
#define CHUNK  256        // i-values per chunk (64 lanes * 4 elements)

__device__ __forceinline__ float qins_decode(int code, int sgn, float d0, float d1) {
    // |w| = exp2(d0 + code*d1); sign bit straight from the int32 sign (+1 / -1)
    const float e = __builtin_amdgcn_exp2f(fmaf((float)code, d1, d0));
    const uint32_t m = ((uint32_t)sgn) & 0x80000000u;
    return __uint_as_float(__float_as_uint(e) ^ m);
}

// load one chunk's codes+signs for this wave's RPW rows (coalesced dwordx4)
#define LOADW(C, G, IPOS)                                                    \
    do {                                                                     \
        _Pragma("unroll")                                                    \
        for (int r = 0; r < RPW; ++r) {                                      \
            const int off = rowbase[r] + (IPOS);                             \
            (C)[r] = *reinterpret_cast<const int4*>(stored + off);           \
            (G)[r] = *reinterpret_cast<const int4*>(sign + off);             \
        }                                                                    \
    } while (0)

#define COMPUTE(C, G, IPOS)                                                  \
    do {                                                                     \
        float w[RPW][4];                                                     \
        _Pragma("unroll")                                                    \
        for (int r = 0; r < RPW; ++r) {                                      \
            w[r][0] = qins_decode((C)[r].x, (G)[r].x, d0, d1);               \
            w[r][1] = qins_decode((C)[r].y, (G)[r].y, d0, d1);               \
            w[r][2] = qins_decode((C)[r].z, (G)[r].z, d0, d1);               \
            w[r][3] = qins_decode((C)[r].w, (G)[r].w, d0, d1);               \
        }                                                                    \
        _Pragma("unroll")                                                    \
        for (int b = 0; b < BATCH; ++b) {                                    \
            const float4 t = *reinterpret_cast<const float4*>(               \
                x + b * IN_F + (IPOS) + ii0);                                \
            _Pragma("unroll")                                                \
            for (int r = 0; r < RPW; ++r) {                                  \
                float a = acc[r][b];                                         \
                a = fmaf(w[r][0], t.x, a);                                   \
                a = fmaf(w[r][1], t.y, a);                                   \
                a = fmaf(w[r][2], t.z, a);                                   \
                a = fmaf(w[r][3], t.w, a);                                   \
                acc[r][b] = a;                                               \
            }                                                                \
        }                                                                    \
    } while (0)

__global__ __launch_bounds__(WAVES*64, 4)
void qins_linear_kernel(const float* __restrict__ x,
                        const int*   __restrict__ stored,
                        const int*   __restrict__ sign,
                        const float* __restrict__ log_min,
                        const float* __restrict__ log_max,
                        const float* __restrict__ bias,
                        float* __restrict__ out)
{
    const int lane = threadIdx.x & 63;
    const int wave = threadIdx.x >> 6;
    const int o0   = blockIdx.x * RPB + wave * RPW;

    const float lmin = log_min[0];
    const float lmax = log_max[0];
    const float L2E  = 1.44269504088896340736f;
    // log2(|w|) = d0 + code*d1
    const float d1 = -(lmax - lmin) * (L2E / 254.0f);
    const float d0 = (lmin + (lmax - lmin) * (255.0f / 254.0f)) * L2E;

    float acc[RPW][BATCH];
#pragma unroll
    for (int r = 0; r < RPW; ++r)
#pragma unroll
        for (int b = 0; b < BATCH; ++b) acc[r][b] = 0.0f;

    const int ii0 = lane * 4;
    int rowbase[RPW];
#pragma unroll
    for (int r = 0; r < RPW; ++r) rowbase[r] = (o0 + r) * IN_F + ii0;

    // register double-buffered weight stream: next chunk in flight while
    // decoding + FMA-ing the current one
    int4 cA[RPW], gA[RPW], cB[RPW], gB[RPW];

    LOADW(cA, gA, 0);
    int i0 = 0;
    for (; i0 < IN_F - 2 * CHUNK; i0 += 2 * CHUNK) {
        LOADW(cB, gB, i0 + CHUNK);
        COMPUTE(cA, gA, i0);
        LOADW(cA, gA, i0 + 2 * CHUNK);
        COMPUTE(cB, gB, i0 + CHUNK);
    }
    LOADW(cB, gB, i0 + CHUNK);
    COMPUTE(cA, gA, i0);
    COMPUTE(cB, gB, i0 + CHUNK);

    // full-wave butterfly reduction for the 16 (row,batch) partials
#pragma unroll
    for (int r = 0; r < RPW; ++r)
#pragma unroll
        for (int b = 0; b < BATCH; ++b) {
            float v = acc[r][b];
#pragma unroll
            for (int s = 32; s >= 1; s >>= 1)
                v += __shfl_xor(v, s, 64);
            acc[r][b] = v;
        }

    if (lane == 0) {
#pragma unroll
        for (int r = 0; r < RPW; ++r) {
            const float bv = bias[o0 + r];
#pragma unroll
            for (int b = 0; b < BATCH; ++b)
                out[(size_t)b * OUT_F + o0 + r] = acc[r][b] + bv;
        }
    }
}

extern "C" void kernel_launch(void* const* d_in, const int* in_sizes, int n_in,
                              void* d_out, int out_size, void* d_ws, size_t ws_size,
                              hipStream_t stream)
{
    const float* x      = (const float*)d_in[0];
    const int*   stored = (const int*)d_in[1];
    const int*   sign   = (const int*)d_in[2];
    const float* lmin   = (const float*)d_in[3];
    const float* lmax   = (const float*)d_in[4];
    const float* bias   = (const float*)d_in[5];
    float* out = (float*)d_out;

    dim3 grid(OUT_F / RPB), block(WAVES * 64);
    qins_linear_kernel<<<grid, block, 0, stream>>>(x, stored, sign, lmin, lmax, bias, out);
}

// Round 6
// 84.761 us; speedup vs baseline: 1.9331x; 1.0372x over previous
//
#include <hip/hip_runtime.h>
#include <stdint.h>

#define IN_F   4096
#define OUT_F  11008
#define BATCH  8
#define RPW    2          // output rows per wave
#define WAVES  4          // waves per block
#define RPB    (RPW*WAVES)
#define CHUNK  256        // i-values per chunk (64 lanes * 4 elements)

__device__ __forceinline__ float qins_decode(int code, int sgn, float d0, float d1) {
    // |w| = exp2(d0 + code*d1); sign bit straight from the int32 sign (+1 / -1)
    const float e = __builtin_amdgcn_exp2f(fmaf((float)code, d1, d0));
    const uint32_t m = ((uint32_t)sgn) & 0x80000000u;
    return __uint_as_float(__float_as_uint(e) ^ m);
}

// Issue x loads for chunk at IPOS (8 float4, L2-hot). MUST be issued before the
// weight loads of the same chunk so vmcnt FIFO retires x no later than weights.
#define LOADX(X, IPOS)                                                       \
    do {                                                                     \
        _Pragma("unroll")                                                    \
        for (int b = 0; b < BATCH; ++b)                                      \
            (X)[b] = *reinterpret_cast<const float4*>(                       \
                x + b * IN_F + (IPOS) + ii0);                                \
    } while (0)

// Issue weight loads for chunk at IPOS (coalesced dwordx4, 4 KB/wave)
#define LOADW(C, G, IPOS)                                                    \
    do {                                                                     \
        _Pragma("unroll")                                                    \
        for (int r = 0; r < RPW; ++r) {                                      \
            const int off = rowbase[r] + (IPOS);                             \
            (C)[r] = *reinterpret_cast<const int4*>(stored + off);           \
            (G)[r] = *reinterpret_cast<const int4*>(sign + off);             \
        }                                                                    \
    } while (0)

// Pure-register compute: decode 8 weights/lane, 64 FMAs
#define COMPUTE(X, C, G)                                                     \
    do {                                                                     \
        float w[RPW][4];                                                     \
        _Pragma("unroll")                                                    \
        for (int r = 0; r < RPW; ++r) {                                      \
            w[r][0] = qins_decode((C)[r].x, (G)[r].x, d0, d1);               \
            w[r][1] = qins_decode((C)[r].y, (G)[r].y, d0, d1);               \
            w[r][2] = qins_decode((C)[r].z, (G)[r].z, d0, d1);               \
            w[r][3] = qins_decode((C)[r].w, (G)[r].w, d0, d1);               \
        }                                                                    \
        _Pragma("unroll")                                                    \
        for (int b = 0; b < BATCH; ++b) {                                    \
            _Pragma("unroll")                                                \
            for (int r = 0; r < RPW; ++r) {                                  \
                float a = acc[r][b];                                         \
                a = fmaf(w[r][0], (X)[b].x, a);                              \
                a = fmaf(w[r][1], (X)[b].y, a);                              \
                a = fmaf(w[r][2], (X)[b].z, a);                              \
                a = fmaf(w[r][3], (X)[b].w, a);                              \
                acc[r][b] = a;                                               \
            }                                                                \
        }                                                                    \
    } while (0)

__global__ __launch_bounds__(WAVES*64, 3)
void qins_linear_kernel(const float* __restrict__ x,
                        const int*   __restrict__ stored,
                        const int*   __restrict__ sign,
                        const float* __restrict__ log_min,
                        const float* __restrict__ log_max,
                        const float* __restrict__ bias,
                        float* __restrict__ out)
{
    const int lane = threadIdx.x & 63;
    const int wave = threadIdx.x >> 6;
    const int o0   = blockIdx.x * RPB + wave * RPW;

    const float lmin = log_min[0];
    const float lmax = log_max[0];
    const float L2E  = 1.44269504088896340736f;
    // log2(|w|) = d0 + code*d1
    const float d1 = -(lmax - lmin) * (L2E / 254.0f);
    const float d0 = (lmin + (lmax - lmin) * (255.0f / 254.0f)) * L2E;

    float acc[RPW][BATCH];
#pragma unroll
    for (int r = 0; r < RPW; ++r)
#pragma unroll
        for (int b = 0; b < BATCH; ++b) acc[r][b] = 0.0f;

    const int ii0 = lane * 4;
    int rowbase[RPW];
#pragma unroll
    for (int r = 0; r < RPW; ++r) rowbase[r] = (o0 + r) * IN_F + ii0;

    // full register double-buffer: x AND weights for the next chunk are always
    // in flight while the current chunk computes from retired registers
    int4   cA[RPW], gA[RPW], cB[RPW], gB[RPW];
    float4 xA[BATCH], xB[BATCH];

    LOADX(xA, 0);
    LOADW(cA, gA, 0);
    int i0 = 0;
    for (; i0 < IN_F - 2 * CHUNK; i0 += 2 * CHUNK) {
        LOADX(xB, i0 + CHUNK);             // x first (vmcnt FIFO!)
        LOADW(cB, gB, i0 + CHUNK);
        COMPUTE(xA, cA, gA);
        LOADX(xA, i0 + 2 * CHUNK);
        LOADW(cA, gA, i0 + 2 * CHUNK);
        COMPUTE(xB, cB, gB);
    }
    LOADX(xB, i0 + CHUNK);
    LOADW(cB, gB, i0 + CHUNK);
    COMPUTE(xA, cA, gA);
    COMPUTE(xB, cB, gB);

    // full-wave butterfly reduction for the 16 (row,batch) partials
#pragma unroll
    for (int r = 0; r < RPW; ++r)
#pragma unroll
        for (int b = 0; b < BATCH; ++b) {
            float v = acc[r][b];
#pragma unroll
            for (int s = 32; s >= 1; s >>= 1)
                v += __shfl_xor(v, s, 64);
            acc[r][b] = v;
        }

    if (lane == 0) {
#pragma unroll
        for (int r = 0; r < RPW; ++r) {
            const float bv = bias[o0 + r];
#pragma unroll
            for (int b = 0; b < BATCH; ++b)
                out[(size_t)b * OUT_F + o0 + r] = acc[r][b] + bv;
        }
    }
}

extern "C" void kernel_launch(void* const* d_in, const int* in_sizes, int n_in,
                              void* d_out, int out_size, void* d_ws, size_t ws_size,
                              hipStream_t stream)
{
    const float* x      = (const float*)d_in[0];
    const int*   stored = (const int*)d_in[1];
    const int*   sign   = (const int*)d_in[2];
    const float* lmin   = (const float*)d_in[3];
    const float* lmax   = (const float*)d_in[4];
    const float* bias   = (const float*)d_in[5];
    float* out = (float*)d_out;

    dim3 grid(OUT_F / RPB), block(WAVES * 64);
    qins_linear_kernel<<<grid, block, 0, stream>>>(x, stored, sign, lmin, lmax, bias, out);
}